// Round 12
// baseline (288.627 us; speedup 1.0000x reference)
//
#include <hip/hip_runtime.h>
#include <math.h>

#define NB 64
#define NT 512
#define ND 768
#define NK 29
#define L2E 1.4426950408889634f
#define LN2 0.6931471805599453f
#define NEG_BIG -1e30f

typedef __attribute__((ext_vector_type(8))) short short8;
typedef __attribute__((ext_vector_type(4))) float floatx4;

__device__ __forceinline__ short bf16r(float f) {   // round-to-nearest-even
    unsigned u = __float_as_uint(f);
    unsigned r = (u + 0x7FFFu + ((u >> 16) & 1u)) >> 16;
    return (short)r;
}

// ---------------------------------------------------------------------------
// Kernel 0: convert w (29x768 fp32) -> wbf (32x768 bf16, rows 29..31 zero)
// ---------------------------------------------------------------------------
__global__ __launch_bounds__(256) void k_prep(const float* __restrict__ w,
                                              short* __restrict__ wbf)
{
    int i = blockIdx.x * 256 + threadIdx.x;            // 32*768 = 24576
    if (i < 32 * ND) {
        int row = i / ND;
        wbf[i] = (row < NK) ? bf16r(w[i]) : (short)0;
    }
}

// ---------------------------------------------------------------------------
// Kernel 1: emissions via bf16 MFMA (bitwise-proven; unchanged).
// ---------------------------------------------------------------------------
__global__ __launch_bounds__(128, 2) void k_emissions(
    const int* __restrict__ x, const float* __restrict__ emb,
    const short* __restrict__ wbf, const float* __restrict__ bias,
    float* __restrict__ em)
{
    __shared__ float red[2 * 256];                     // wave1 partials
    const int lane = threadIdx.x & 63;
    const int wv = threadIdx.x >> 6;                   // d-half (0/1)
    const int col = lane & 15;                         // m for A, n for B
    const int quad = lane >> 4;                        // k-subrange selector
    const int Mbase = blockIdx.x * 16;
    const int tok = Mbase + col;

    const float* arow = emb + (size_t)x[tok] * ND + wv * 384 + quad * 8;
    const short* brow0 = wbf + (size_t)col * ND + wv * 384 + quad * 8;
    const short* brow1 = brow0 + 16 * ND;

    // issue ALL A loads first: 24 x global_load_dwordx4 in flight
    float4 a[24];
#pragma unroll
    for (int c = 0; c < 12; ++c) {
        a[2 * c]     = *(const float4*)(arow + c * 32);
        a[2 * c + 1] = *(const float4*)(arow + c * 32 + 4);
    }

    floatx4 acc0 = {0.f, 0.f, 0.f, 0.f};
    floatx4 acc1 = {0.f, 0.f, 0.f, 0.f};

    short8 b0 = *(const short8*)(brow0);               // B is L2-hot (45 KB)
    short8 b1 = *(const short8*)(brow1);

#pragma unroll
    for (int c = 0; c < 12; ++c) {
        int c1 = (c + 1 <= 11) ? c + 1 : 11;           // clamped prefetch
        short8 nb0 = *(const short8*)(brow0 + c1 * 32);
        short8 nb1 = *(const short8*)(brow1 + c1 * 32);

        short8 af;
        af[0] = bf16r(a[2 * c].x);     af[1] = bf16r(a[2 * c].y);
        af[2] = bf16r(a[2 * c].z);     af[3] = bf16r(a[2 * c].w);
        af[4] = bf16r(a[2 * c + 1].x); af[5] = bf16r(a[2 * c + 1].y);
        af[6] = bf16r(a[2 * c + 1].z); af[7] = bf16r(a[2 * c + 1].w);

        acc0 = __builtin_amdgcn_mfma_f32_16x16x32_bf16(af, b0, acc0, 0, 0, 0);
        acc1 = __builtin_amdgcn_mfma_f32_16x16x32_bf16(af, b1, acc1, 0, 0, 0);

        b0 = nb0; b1 = nb1;
    }

    // reduce the two d-halves; C/D layout: row = quad*4+reg, col = lane&15
    const int r0 = quad * 4;
    if (wv == 1) {
#pragma unroll
        for (int reg = 0; reg < 4; ++reg) {
            red[(r0 + reg) * 16 + col]       = acc0[reg];
            red[256 + (r0 + reg) * 16 + col] = acc1[reg];
        }
    }
    __syncthreads();
    if (wv == 0) {
        float bs0 = bias[col];
        float bs1 = (col < NK - 16) ? bias[16 + col] : 0.f;
#pragma unroll
        for (int reg = 0; reg < 4; ++reg) {
            int row = r0 + reg;
            float v0 = acc0[reg] + red[row * 16 + col] + bs0;
            em[(size_t)(Mbase + row) * NK + col] = v0;
            if (col < NK - 16) {
                float v1 = acc1[reg] + red[256 + row * 16 + col] + bs1;
                em[(size_t)(Mbase + row) * NK + 16 + col] = v1;
            }
        }
    }
}

// ---------------------------------------------------------------------------
// Kernel 2: serial scans, lane-half split, cross-half combine via
// __shfl_xor(x,32) — the ONLY cross-half primitive with absmax-0 provenance
// on this problem (R0's s=32 reduction steps). permlane32_swap is BANNED:
// R1/R10 both flipped decode elements with it (absmax 19) despite
// commutative-combine proofs; its return convention is not as modeled.
// CRF: half A (lanes 0-31) runs R0's exact p0,p1 fmaf chains; half B
//   (lanes 32+c, same col) runs p2,p3. s=ph0+ph1; anew=(s+shfl_xor(s,32))
//   *eemc — commutative fadd == R0's (p0+p1)+(p2+p3) bitwise.
// Viterbi values-only: half maxes 16 candidates (exact tree);
//   fmaxf(mh, shfl_xor(mh,32)) = exact global max -> states bitwise == R5.
// ---------------------------------------------------------------------------
__global__ __launch_bounds__(64) void k_scan(
    const float* __restrict__ em, const int* __restrict__ tags,
    const float* __restrict__ st, const float* __restrict__ en,
    const float* __restrict__ tr, float* __restrict__ part,
    float* __restrict__ states)
{
    __shared__ __align__(16) float sA[32];
    __shared__ __align__(16) unsigned char smem[NT * NK * 4];
    const int lane = threadIdx.x;
    const int c = lane & 31;                           // column owned
    const int h = lane >> 5;                           // chain-half
    const int jc = (c < NK) ? c : NK - 1;

    if (blockIdx.x < NB) {
        // ----------------- CRF forward (R0 chains, split p01/p23) ----------
        const int b = blockIdx.x;
        float* emS = (float*)smem;                     // [512][29]
        {
            const float4* src = (const float4*)(em + (size_t)b * NT * NK);
            float4* dst = (float4*)emS;
            for (int i = lane; i < NT * NK / 4; i += 64) dst[i] = src[i];
        }
        // half A: rows {4ii+0,4ii+1} (p0,p1); half B: rows {4ii+2,4ii+3}
        float EC0[8], EC1[8];
#pragma unroll
        for (int ii = 0; ii < 8; ++ii) {
            int i0 = 4 * ii + 2 * h, i1 = i0 + 1;
            EC0[ii] = (i0 < NK) ? __expf(tr[i0 * NK + jc]) : 0.f;
            EC1[ii] = (i1 < NK) ? __expf(tr[i1 * NK + jc]) : 0.f;
        }
        const float2* sA2 = (const float2*)sA;

        float a0v = __expf(st[jc] + emS[jc]);
        if (lane < 32) sA[lane] = (lane < NK) ? a0v : 0.f;

        int eshift = 5 * (NT - 1);
        float eemc = exp2f(fmaf(emS[NK + jc], L2E, -5.0f));
        float rawn = emS[2 * NK + jc];
        float anew = a0v;

        for (int t = 1; t < NT; ++t) {
            float2 q[8];
#pragma unroll
            for (int ii = 0; ii < 8; ++ii) q[ii] = sA2[2 * ii + h]; // broadcast
            float ph0 = 0.f, ph1 = 0.f;
#pragma unroll
            for (int ii = 0; ii < 8; ++ii) {           // R0's exact chains
                ph0 = fmaf(q[ii].x, EC0[ii], ph0);
                ph1 = fmaf(q[ii].y, EC1[ii], ph1);
            }
            float s = ph0 + ph1;                       // (p0+p1) / (p2+p3)
            float sp = __shfl_xor(s, 32);              // partner half-sum
            anew = (s + sp) * eemc;                    // commutative == R0
            // refill (off critical chain)
            eemc = exp2f(fmaf(rawn, L2E, -5.0f));
            int tn = t + 2; tn = tn < NT ? tn : NT - 1;
            rawn = emS[tn * NK + jc];

            if ((t & 15) == 0) {       // exact pow2 renorm via lane-0 probe
                unsigned mb = (unsigned)__builtin_amdgcn_readfirstlane(
                                  __float_as_int(anew));
                int ex = (int)((mb >> 23) & 255u) - 127;
                anew *= __int_as_float((unsigned)(127 - ex) << 23);
                eshift += ex;
            }
            if (lane < 32) sA[lane] = (lane < NK) ? anew : 0.f;
        }
        float val = (lane < NK) ? anew * __expf(en[jc]) : 0.f;
#pragma unroll
        for (int s = 32; s; s >>= 1) val += __shfl_xor(val, s);
        float logZ = logf(val) + (float)eshift * LN2;
        const int* tg = tags + b * NT;
        float p = 0.f;
        for (int t = lane; t < NT; t += 64) {
            int tt = tg[t];
            p += emS[t * NK + tt];
            if (t == 0) p += st[tt];
            else        p += tr[tg[t - 1] * NK + tt];
            if (t == NT - 1) p += en[tt];
        }
#pragma unroll
        for (int s = 32; s; s >>= 1) p += __shfl_xor(p, s);
        if (lane == 0) part[b] = logZ - p;
    } else {
        // ------------- Viterbi forward, values-only, half-split ------------
        const int b = blockIdx.x - NB;
        const float* emb_b = em + (size_t)b * NT * NK;
        float* stt = states + (size_t)b * NT * 32;     // padded rows

        float Tch[16];                                 // rows [16h,16h+16)
#pragma unroll
        for (int r = 0; r < 16; ++r) {
            int i = 16 * h + r;
            Tch[r] = (i < NK) ? tr[i * NK + jc] : 0.f;
        }
        const float4* sAh4 = (const float4*)(sA + 16 * h);

        float sc = (lane < NK) ? (st[jc] + emb_b[jc]) : NEG_BIG;
        if (lane < 32) { sA[lane] = sc; stt[lane] = sc; } // rows 29..31 NEG_BIG

        float e0 = emb_b[1 * NK + jc];
        float e1 = emb_b[2 * NK + jc];
        float e2 = emb_b[3 * NK + jc];
        float e3 = emb_b[4 * NK + jc];

        auto vstep = [&](int t, float emt) {
            float4 q0 = sAh4[0], q1 = sAh4[1], q2 = sAh4[2], q3 = sAh4[3];
            float v0  = q0.x + Tch[0],  v1  = q0.y + Tch[1];
            float v2  = q0.z + Tch[2],  v3  = q0.w + Tch[3];
            float v4  = q1.x + Tch[4],  v5  = q1.y + Tch[5];
            float v6  = q1.z + Tch[6],  v7  = q1.w + Tch[7];
            float v8  = q2.x + Tch[8],  v9  = q2.y + Tch[9];
            float v10 = q2.z + Tch[10], v11 = q2.w + Tch[11];
            float v12 = q3.x + Tch[12], v13 = q3.y + Tch[13];
            float v14 = q3.z + Tch[14], v15 = q3.w + Tch[15];
            float m0 = fmaxf(v0, v1),   m1 = fmaxf(v2, v3);
            float m2 = fmaxf(v4, v5),   m3 = fmaxf(v6, v7);
            float m4 = fmaxf(v8, v9),   m5 = fmaxf(v10, v11);
            float m6 = fmaxf(v12, v13), m7 = fmaxf(v14, v15);
            float n0 = fmaxf(m0, m1), n1 = fmaxf(m2, m3);
            float n2 = fmaxf(m4, m5), n3 = fmaxf(m6, m7);
            float mh = fmaxf(fmaxf(n0, n1), fmaxf(n2, n3)); // half max (exact)
            float m = fmaxf(mh, __shfl_xor(mh, 32));   // exact global max
            sc = (lane < NK) ? (m + emt) : NEG_BIG;
            if (lane < 32) { sA[lane] = sc; stt[t * 32 + lane] = sc; }
        };

        int t = 1;
        for (; t + 3 < NT; t += 4) {
            vstep(t + 0, e0); { int tn = t + 4; tn = tn < NT ? tn : NT - 1; e0 = emb_b[tn * NK + jc]; }
            vstep(t + 1, e1); { int tn = t + 5; tn = tn < NT ? tn : NT - 1; e1 = emb_b[tn * NK + jc]; }
            vstep(t + 2, e2); { int tn = t + 6; tn = tn < NT ? tn : NT - 1; e2 = emb_b[tn * NK + jc]; }
            vstep(t + 3, e3); { int tn = t + 7; tn = tn < NT ? tn : NT - 1; e3 = emb_b[tn * NK + jc]; }
        }
        vstep(509, e0); vstep(510, e1); vstep(511, e2);
        // finals + backtrace in k_post
    }
}

// ---------------------------------------------------------------------------
// Kernel 2b: fused bp + trace + finish (R10 structure; R9-verbatim bodies).
// 64 blocks x 512 thr, (512,1). Stage 512 state rows to LDS (64 KB),
// 16 half-waves recompute bp (straight-line exact-max + descending first-max
// select == np.argmax), barrier, wave 0 runs the segmented backtrace;
// block 0 wave 1 sums part[] into out[0].
// ---------------------------------------------------------------------------
__global__ __launch_bounds__(512, 1) void k_post(
    const float* __restrict__ states, const float* __restrict__ tr,
    const float* __restrict__ en, const float* __restrict__ part,
    float* __restrict__ out)
{
    __shared__ __align__(16) float stt[NT * 32];           // 64 KB
    __shared__ __align__(16) unsigned char sbp[511 * 32];  // 16 KB
    __shared__ unsigned char smap[16 * 32];
    const int b = blockIdx.x;
    const int tid = threadIdx.x;
    const int c = tid & 31;
    const int w = tid >> 5;                                // half-wave 0..15
    const int jc = (c < NK) ? c : NK - 1;

    {   // stage all 512 state rows (4096 float4), coalesced
        const float4* src = (const float4*)(states + (size_t)b * NT * 32);
        float4* dst = (float4*)stt;
#pragma unroll
        for (int i = 0; i < 8; ++i) dst[tid + 512 * i] = src[tid + 512 * i];
    }

    float Tc[32];                                          // static idx only
#pragma unroll
    for (int i = 0; i < NK; ++i) Tc[i] = tr[i * NK + jc];
#pragma unroll
    for (int i = NK; i < 32; ++i) Tc[i] = 0.f;

    __syncthreads();

#pragma unroll 1
    for (int k = 0; k < 32; ++k) {
        int rr = 32 * w + k;                               // bp row rr
        if (rr <= 510) {
            const float4* row = (const float4*)(stt + rr * 32);
            float4 q0 = row[0], q1 = row[1], q2 = row[2], q3 = row[3];
            float4 q4 = row[4], q5 = row[5], q6 = row[6], q7 = row[7];
            float v0  = q0.x + Tc[0],  v1  = q0.y + Tc[1];
            float v2  = q0.z + Tc[2],  v3  = q0.w + Tc[3];
            float v4  = q1.x + Tc[4],  v5  = q1.y + Tc[5];
            float v6  = q1.z + Tc[6],  v7  = q1.w + Tc[7];
            float v8  = q2.x + Tc[8],  v9  = q2.y + Tc[9];
            float v10 = q2.z + Tc[10], v11 = q2.w + Tc[11];
            float v12 = q3.x + Tc[12], v13 = q3.y + Tc[13];
            float v14 = q3.z + Tc[14], v15 = q3.w + Tc[15];
            float v16 = q4.x + Tc[16], v17 = q4.y + Tc[17];
            float v18 = q4.z + Tc[18], v19 = q4.w + Tc[19];
            float v20 = q5.x + Tc[20], v21 = q5.y + Tc[21];
            float v22 = q5.z + Tc[22], v23 = q5.w + Tc[23];
            float v24 = q6.x + Tc[24], v25 = q6.y + Tc[25];
            float v26 = q6.z + Tc[26], v27 = q6.w + Tc[27];
            float v28 = q7.x + Tc[28], v29 = q7.y + Tc[29];
            float v30 = q7.z + Tc[30], v31 = q7.w + Tc[31];
            float m0 = fmaxf(v0, v1),   m1 = fmaxf(v2, v3);
            float m2 = fmaxf(v4, v5),   m3 = fmaxf(v6, v7);
            float m4 = fmaxf(v8, v9),   m5 = fmaxf(v10, v11);
            float m6 = fmaxf(v12, v13), m7 = fmaxf(v14, v15);
            float m8 = fmaxf(v16, v17), m9 = fmaxf(v18, v19);
            float ma = fmaxf(v20, v21), mb = fmaxf(v22, v23);
            float mc = fmaxf(v24, v25), md = fmaxf(v26, v27);
            float me = fmaxf(v28, v29), mf = fmaxf(v30, v31);
            float n0 = fmaxf(m0, m1), n1 = fmaxf(m2, m3);
            float n2 = fmaxf(m4, m5), n3 = fmaxf(m6, m7);
            float n4 = fmaxf(m8, m9), n5 = fmaxf(ma, mb);
            float n6 = fmaxf(mc, md), n7 = fmaxf(me, mf);
            float o0 = fmaxf(n0, n1), o1 = fmaxf(n2, n3);
            float o2 = fmaxf(n4, n5), o3 = fmaxf(n6, n7);
            float m  = fmaxf(fmaxf(o0, o1), fmaxf(o2, o3));
            int idx = 31;
            idx = (v30 == m) ? 30 : idx;  idx = (v29 == m) ? 29 : idx;
            idx = (v28 == m) ? 28 : idx;  idx = (v27 == m) ? 27 : idx;
            idx = (v26 == m) ? 26 : idx;  idx = (v25 == m) ? 25 : idx;
            idx = (v24 == m) ? 24 : idx;  idx = (v23 == m) ? 23 : idx;
            idx = (v22 == m) ? 22 : idx;  idx = (v21 == m) ? 21 : idx;
            idx = (v20 == m) ? 20 : idx;  idx = (v19 == m) ? 19 : idx;
            idx = (v18 == m) ? 18 : idx;  idx = (v17 == m) ? 17 : idx;
            idx = (v16 == m) ? 16 : idx;  idx = (v15 == m) ? 15 : idx;
            idx = (v14 == m) ? 14 : idx;  idx = (v13 == m) ? 13 : idx;
            idx = (v12 == m) ? 12 : idx;  idx = (v11 == m) ? 11 : idx;
            idx = (v10 == m) ? 10 : idx;  idx = (v9  == m) ? 9  : idx;
            idx = (v8  == m) ? 8  : idx;  idx = (v7  == m) ? 7  : idx;
            idx = (v6  == m) ? 6  : idx;  idx = (v5  == m) ? 5  : idx;
            idx = (v4  == m) ? 4  : idx;  idx = (v3  == m) ? 3  : idx;
            idx = (v2  == m) ? 2  : idx;  idx = (v1  == m) ? 1  : idx;
            idx = (v0  == m) ? 0  : idx;
            sbp[rr * 32 + c] = (unsigned char)idx;
        }
    }
    __syncthreads();

    if (tid < 64) {    // wave 0: finals + segmented backtrace (verbatim)
        const int lane = tid;
        float sv = stt[511 * 32 + ((lane < 32) ? lane : 0)];
        float vfin = (lane < NK) ? (sv + en[jc]) : NEG_BIG;
        float M = vfin;
#pragma unroll
        for (int s = 32; s; s >>= 1) M = fmaxf(M, __shfl_xor(M, s));
        unsigned long long mk = __ballot((lane < NK) && vfin == M);
        int last = (int)__builtin_ctzll(mk);

        const int cl = lane & 31;
        const int hh = lane >> 5;
        int cur8[8];
#pragma unroll
        for (int rep = 0; rep < 8; ++rep) cur8[rep] = cl;
        for (int off = 0; off < 32; ++off) {
#pragma unroll
            for (int rep = 0; rep < 8; ++rep) {
                int s = 2 * rep + hh;
                int hi = (s == 15) ? 511 : 32 * s + 32;
                int r = hi - 1 - off;
                if (r >= 32 * s) cur8[rep] = sbp[r * 32 + cur8[rep]];
            }
        }
#pragma unroll
        for (int rep = 0; rep < 8; ++rep)
            smap[(2 * rep + hh) * 32 + cl] = (unsigned char)cur8[rep];

        int myhi = 0, cur = last;
        for (int s = 15; s >= 0; --s) {
            if (lane == s) myhi = cur;
            cur = smap[s * 32 + cur];
        }
        float* op = out + 1 + (size_t)b * NT;
        if (lane == 16) op[NT - 1] = (float)last;
        if (lane < 16) {
            int s = lane;
            int hi = (s == 15) ? 511 : 32 * s + 32;
            int cc = myhi;
            for (int r = hi - 1; r >= 32 * s; --r) {
                cc = sbp[r * 32 + cc];
                op[r] = (float)cc;
            }
        }
    } else if (b == 0 && tid < 128) {   // block 0, wave 1: nll reduction
        int l2 = tid - 64;
        float v = part[l2];
#pragma unroll
        for (int s = 32; s; s >>= 1) v += __shfl_xor(v, s);
        if (l2 == 0) out[0] = v;
    }
}

extern "C" void kernel_launch(void* const* d_in, const int* in_sizes, int n_in,
                              void* d_out, int out_size, void* d_ws, size_t ws_size,
                              hipStream_t stream) {
    const int*   x    = (const int*)d_in[0];
    const int*   tags = (const int*)d_in[1];
    const float* emb  = (const float*)d_in[2];
    const float* w    = (const float*)d_in[3];
    const float* bias = (const float*)d_in[4];
    const float* st   = (const float*)d_in[5];
    const float* en   = (const float*)d_in[6];
    const float* tr   = (const float*)d_in[7];
    float* out = (float*)d_out;

    short* wbf    = (short*)d_ws;                            // 48 KB
    float* part   = (float*)((char*)d_ws + 49152);           // 256 B
    float* em     = (float*)((char*)d_ws + 65536);           // 3.80 MB
    float* states = (float*)((char*)d_ws + 3932160);         // 4.19 MB (ws ~8.2 MB)

    k_prep<<<96, 256, 0, stream>>>(w, wbf);
    k_emissions<<<2048, 128, 0, stream>>>(x, emb, wbf, bias, em);
    k_scan<<<2 * NB, 64, 0, stream>>>(em, tags, st, en, tr, part, states);
    k_post<<<NB, 512, 0, stream>>>(states, tr, en, part, out);
}